// Round 1
// baseline (4284.971 us; speedup 1.0000x reference)
//
#include <hip/hip_runtime.h>
#include <stdint.h>

typedef unsigned short u16;
typedef _Float16 f16x8 __attribute__((ext_vector_type(8)));
typedef float f32x4 __attribute__((ext_vector_type(4)));

#define B_ROWS 8192
#define K_DIM  4096
#define H_DIM  8192
#define W_SCALE 64.0f
#define INV_W_SCALE 0.015625f

// ---------- f16 helpers (RNE via v_cvt_f16_f32) ----------
__device__ __forceinline__ u16 f2h_bits(float f) {
  _Float16 h = (_Float16)f;
  return __builtin_bit_cast(u16, h);
}
__device__ __forceinline__ float h2f(u16 u) {
  return (float)__builtin_bit_cast(_Float16, u);
}

// ---------- direct global->LDS (width 16) ----------
typedef __attribute__((address_space(1))) void gvoid_t;
typedef __attribute__((address_space(3))) void lvoid_t;
#define GLOAD_LDS16(gp, lp) \
  __builtin_amdgcn_global_load_lds((gvoid_t*)(gp), (lvoid_t*)(lp), 16, 0, 0)

// ---------- x: fp32 -> f16 hi + f16 lo ----------
__global__ void split_x_kernel(const float4* __restrict__ x,
                               ushort4* __restrict__ hi,
                               ushort4* __restrict__ lo, int n4) {
  int i = blockIdx.x * blockDim.x + threadIdx.x;
  if (i >= n4) return;
  float4 v = x[i];
  ushort4 h, l;
  h.x = f2h_bits(v.x); l.x = f2h_bits(v.x - h2f(h.x));
  h.y = f2h_bits(v.y); l.y = f2h_bits(v.y - h2f(h.y));
  h.z = f2h_bits(v.z); l.z = f2h_bits(v.z - h2f(h.z));
  h.w = f2h_bits(v.w); l.w = f2h_bits(v.w - h2f(h.w));
  hi[i] = h; lo[i] = l;
}

// ---------- w1 [D,H] fp32 -> w1T [H,D] f16 hi (+lo), scaled by 64 ----------
__global__ void transpose_split_kernel(const float* __restrict__ w,
                                       u16* __restrict__ hi, u16* __restrict__ lo,
                                       int rows, int cols) {
  __shared__ float tile[32][33];
  int c0 = blockIdx.x * 32, r0 = blockIdx.y * 32;
  int tx = threadIdx.x, ty = threadIdx.y;
  #pragma unroll
  for (int j = 0; j < 4; ++j)
    tile[ty + j*8][tx] = w[(size_t)(r0 + ty + j*8) * cols + c0 + tx];
  __syncthreads();
  #pragma unroll
  for (int j = 0; j < 4; ++j) {
    int oc = c0 + ty + j*8;                 // output row = original col (h)
    float v = tile[tx][ty + j*8] * W_SCALE; // scale keeps lo-part in f16 normal range
    u16 h = f2h_bits(v);
    size_t oidx = (size_t)oc * rows + r0 + tx;
    hi[oidx] = h;
    if (lo) lo[oidx] = f2h_bits(v - h2f(h));
  }
}

// ---------- init logit accumulators with b2 ----------
__global__ void init_parts_kernel(float* __restrict__ tp, float* __restrict__ fp,
                                  const float* __restrict__ tb2,
                                  const float* __restrict__ fb2) {
  int i = blockIdx.x * blockDim.x + threadIdx.x;
  if (i < 2 * B_ROWS) { tp[i] = tb2[i & 1]; fp[i] = fb2[i & 1]; }
}

// ---------- fused MLP GEMM ----------
// A segs: [B_ROWS][K] f16-as-u16 row-major.  B segs: w1T [H][K] (scaled by 64).
// acc = sum_seg A_seg @ B_seg^T ; epilogue: h = relu(acc/64 + b1[n]);
// out_part[m][c] += sum_n h*w2[n][c]  (atomic, over n-blocks).
__global__ __launch_bounds__(256) void mlp_gemm_kernel(
    const u16* __restrict__ A0, const u16* __restrict__ B0,
    const u16* __restrict__ A1, const u16* __restrict__ B1,
    const u16* __restrict__ A2, const u16* __restrict__ B2,
    int nseg,
    const float* __restrict__ bias1,
    const float* __restrict__ w2,
    float* __restrict__ out_part)
{
  // LDS in MFMA-fragment order: 16 groups of 64 chunks(16B) for A, same for B.
  // group g = ((half*4 + t16)*2 + s): lane l=q*16+r holds row(t16*16+r), k(s*32+q*8..+7)
  __shared__ u16 lds[16384];   // 32 KB: A at [0..8191], B at [8192..16383]

  const int tid  = threadIdx.x;
  const int lane = tid & 63;
  const int wave = tid >> 6;
  const int wm = wave >> 1;    // 2x2 wave grid; each wave does 64x64
  const int wn = wave & 1;
  const int q  = lane >> 4;
  const int r  = lane & 15;

  const int bm = blockIdx.y;
  const int bn = blockIdx.x;

  // writer side: wave issues groups g = wave*4+j (4 A + 4 B loads per iter)
  unsigned a_off[4], b_off[4];
  int lA[4], lB[4];
  #pragma unroll
  for (int j = 0; j < 4; ++j) {
    int g  = wave * 4 + j;
    int hg = g >> 3, tg = (g >> 1) & 3, sg = g & 1;
    int rowa = bm * 128 + hg * 64 + tg * 16 + r;
    int rowb = bn * 128 + hg * 64 + tg * 16 + r;
    int col  = sg * 32 + q * 8;
    a_off[j] = (unsigned)rowa * K_DIM + col;
    b_off[j] = (unsigned)rowb * K_DIM + col;
    lA[j] = g * 512;
    lB[j] = 8192 + g * 512;
  }

  f32x4 acc[4][4];
  #pragma unroll
  for (int i = 0; i < 4; ++i)
    #pragma unroll
    for (int j = 0; j < 4; ++j)
      acc[i][j] = (f32x4){0.f, 0.f, 0.f, 0.f};

  const u16* As[3] = {A0, A1, A2};
  const u16* Bs[3] = {B0, B1, B2};

  for (int sg = 0; sg < nseg; ++sg) {
    const u16* Ab = As[sg];
    const u16* Bb = Bs[sg];
    for (int kk = 0; kk < K_DIM / 64; ++kk) {
      const unsigned kadd = (unsigned)kk * 64u;
      __syncthreads();                       // prior compute done before overwrite
      #pragma unroll
      for (int j = 0; j < 4; ++j) {
        GLOAD_LDS16(Ab + a_off[j] + kadd, &lds[lA[j]]);
        GLOAD_LDS16(Bb + b_off[j] + kadd, &lds[lB[j]]);
      }
      __syncthreads();                       // vmcnt(0) drain before barrier
      #pragma unroll
      for (int s = 0; s < 2; ++s) {
        f16x8 av[4], bv[4];
        #pragma unroll
        for (int t = 0; t < 4; ++t) {
          av[t] = *reinterpret_cast<const f16x8*>(&lds[((wm*4 + t)*2 + s)*512 + lane*8]);
          bv[t] = *reinterpret_cast<const f16x8*>(&lds[8192 + ((wn*4 + t)*2 + s)*512 + lane*8]);
        }
        #pragma unroll
        for (int tm = 0; tm < 4; ++tm)
          #pragma unroll
          for (int tn = 0; tn < 4; ++tn)
            acc[tm][tn] = __builtin_amdgcn_mfma_f32_16x16x32_f16(av[tm], bv[tn], acc[tm][tn], 0, 0, 0);
      }
    }
  }

  // ---- fused layer-2 epilogue ----
  // C/D layout (16x16x32): col = lane&15, row = q*4 + reg
  const int nbase = bn * 128 + wn * 64 + r;
  float b1v[4], w20[4], w21[4];
  #pragma unroll
  for (int t = 0; t < 4; ++t) {
    int n = nbase + t * 16;
    b1v[t] = bias1[n];
    w20[t] = w2[2*n];
    w21[t] = w2[2*n + 1];
  }
  const int mbase = bm * 128 + wm * 64 + q * 4;
  #pragma unroll
  for (int tm = 0; tm < 4; ++tm) {
    #pragma unroll
    for (int v = 0; v < 4; ++v) {
      float s0 = 0.f, s1 = 0.f;
      #pragma unroll
      for (int tn = 0; tn < 4; ++tn) {
        float h = fmaxf(fmaf(acc[tm][tn][v], INV_W_SCALE, b1v[tn]), 0.f);
        s0 = fmaf(h, w20[tn], s0);
        s1 = fmaf(h, w21[tn], s1);
      }
      #pragma unroll
      for (int off = 1; off < 16; off <<= 1) {   // reduce over 16 cols (lane&15)
        s0 += __shfl_xor(s0, off, 64);
        s1 += __shfl_xor(s1, off, 64);
      }
      if (r == 0) {
        int m = mbase + tm * 16 + v;
        atomicAdd(&out_part[2*m],     s0);
        atomicAdd(&out_part[2*m + 1], s1);
      }
    }
  }
}

// ---------- confidence select ----------
__global__ void select_kernel(const float* __restrict__ tp, const float* __restrict__ fp,
                              float* __restrict__ out) {
  int m = blockIdx.x * blockDim.x + threadIdx.x;
  if (m >= B_ROWS) return;
  float a = tp[2*m], b = tp[2*m + 1];
  float conf = 1.0f / (1.0f + expf(-fabsf(a - b)));  // = max softmax prob, C=2
  bool low = conf < 0.8f;
  out[2*m]     = low ? fp[2*m]     : a;
  out[2*m + 1] = low ? fp[2*m + 1] : b;
}

extern "C" void kernel_launch(void* const* d_in, const int* in_sizes, int n_in,
                              void* d_out, int out_size, void* d_ws, size_t ws_size,
                              hipStream_t stream) {
  const float* x    = (const float*)d_in[0];
  const float* t_w1 = (const float*)d_in[1];
  const float* t_b1 = (const float*)d_in[2];
  const float* t_w2 = (const float*)d_in[3];
  const float* t_b2 = (const float*)d_in[4];
  const float* f_w1 = (const float*)d_in[5];
  const float* f_b1 = (const float*)d_in[6];
  const float* f_w2 = (const float*)d_in[7];
  const float* f_b2 = (const float*)d_in[8];
  float* out = (float*)d_out;

  const size_t SZ = (size_t)B_ROWS * K_DIM * sizeof(u16);   // 64 MB
  const size_t NEED = 5 * SZ + 2 * (size_t)(2 * B_ROWS) * sizeof(float);
  if (ws_size < NEED) return;  // workspace too small (constant per session)

  char* ws = (char*)d_ws;
  u16* x_hi   = (u16*)(ws);
  u16* x_lo   = (u16*)(ws + SZ);
  u16* twT_hi = (u16*)(ws + 2 * SZ);
  u16* twT_lo = (u16*)(ws + 3 * SZ);
  u16* fwT_hi = (u16*)(ws + 4 * SZ);
  float* t_part = (float*)(ws + 5 * SZ);
  float* f_part = t_part + 2 * B_ROWS;

  // conversions
  split_x_kernel<<<(B_ROWS * K_DIM / 4 + 255) / 256, 256, 0, stream>>>(
      (const float4*)x, (ushort4*)x_hi, (ushort4*)x_lo, B_ROWS * K_DIM / 4);
  dim3 tb(32, 8);
  transpose_split_kernel<<<dim3(H_DIM / 32, K_DIM / 32), tb, 0, stream>>>(
      t_w1, twT_hi, twT_lo, K_DIM, H_DIM);
  transpose_split_kernel<<<dim3(H_DIM / 32, K_DIM / 32), tb, 0, stream>>>(
      f_w1, fwT_hi, nullptr, K_DIM, H_DIM);
  init_parts_kernel<<<(2 * B_ROWS + 255) / 256, 256, 0, stream>>>(
      t_part, f_part, t_b2, f_b2);

  // texture expert: split-precision, 3 segments -> ~fp32-accurate logits
  dim3 grid(H_DIM / 128, B_ROWS / 128);
  mlp_gemm_kernel<<<grid, 256, 0, stream>>>(
      x_hi, twT_hi, x_lo, twT_hi, x_hi, twT_lo, 3, t_b1, t_w2, t_part);
  // frequency expert: plain f16 (value accuracy only)
  mlp_gemm_kernel<<<grid, 256, 0, stream>>>(
      x_hi, fwT_hi, x_hi, fwT_hi, x_hi, fwT_hi, 1, f_b1, f_w2, f_part);

  select_kernel<<<(B_ROWS + 255) / 256, 256, 0, stream>>>(t_part, f_part, out);
}

// Round 2
// 3116.376 us; speedup vs baseline: 1.3750x; 1.3750x over previous
//
#include <hip/hip_runtime.h>
#include <stdint.h>

typedef unsigned short u16;
typedef _Float16 f16x8 __attribute__((ext_vector_type(8)));
typedef float f32x4 __attribute__((ext_vector_type(4)));

#define B_ROWS 8192
#define K_DIM  4096
#define H_DIM  8192
#define W_SCALE 64.0f
#define INV_W_SCALE 0.015625f

// ---------- f16 helpers ----------
__device__ __forceinline__ u16 f2h_bits(float f) {
  _Float16 h = (_Float16)f;
  return __builtin_bit_cast(u16, h);
}
__device__ __forceinline__ float h2f(u16 u) {
  return (float)__builtin_bit_cast(_Float16, u);
}

// ---------- direct global->LDS (width 16) ----------
typedef __attribute__((address_space(1))) void gvoid_t;
typedef __attribute__((address_space(3))) void lvoid_t;
#define GLOAD_LDS16(gp, lp) \
  __builtin_amdgcn_global_load_lds((gvoid_t*)(gp), (lvoid_t*)(lp), 16, 0, 0)

// ---------- x: fp32 -> f16 hi + f16 lo ----------
__global__ void split_x_kernel(const float4* __restrict__ x,
                               ushort4* __restrict__ hi,
                               ushort4* __restrict__ lo, int n4) {
  int i = blockIdx.x * blockDim.x + threadIdx.x;
  if (i >= n4) return;
  float4 v = x[i];
  ushort4 h, l;
  h.x = f2h_bits(v.x); l.x = f2h_bits(v.x - h2f(h.x));
  h.y = f2h_bits(v.y); l.y = f2h_bits(v.y - h2f(h.y));
  h.z = f2h_bits(v.z); l.z = f2h_bits(v.z - h2f(h.z));
  h.w = f2h_bits(v.w); l.w = f2h_bits(v.w - h2f(h.w));
  hi[i] = h; lo[i] = l;
}

// ---------- w1 [D,H] fp32 -> w1T [H,D] f16 hi (+lo), scaled by 64 ----------
__global__ void transpose_split_kernel(const float* __restrict__ w,
                                       u16* __restrict__ hi, u16* __restrict__ lo,
                                       int rows, int cols) {
  __shared__ float tile[32][33];
  int c0 = blockIdx.x * 32, r0 = blockIdx.y * 32;
  int tx = threadIdx.x, ty = threadIdx.y;
  #pragma unroll
  for (int j = 0; j < 4; ++j)
    tile[ty + j*8][tx] = w[(size_t)(r0 + ty + j*8) * cols + c0 + tx];
  __syncthreads();
  #pragma unroll
  for (int j = 0; j < 4; ++j) {
    int oc = c0 + ty + j*8;
    float v = tile[tx][ty + j*8] * W_SCALE;
    u16 h = f2h_bits(v);
    size_t oidx = (size_t)oc * rows + r0 + tx;
    hi[oidx] = h;
    if (lo) lo[oidx] = f2h_bits(v - h2f(h));
  }
}

// ---------- init logit accumulators with b2 ----------
__global__ void init_parts_kernel(float* __restrict__ tp, float* __restrict__ fp,
                                  const float* __restrict__ tb2,
                                  const float* __restrict__ fb2) {
  int i = blockIdx.x * blockDim.x + threadIdx.x;
  if (i < 2 * B_ROWS) { tp[i] = tb2[i & 1]; fp[i] = fb2[i & 1]; }
}

// ---------- fused layer-2 epilogue helper ----------
// C/D layout (16x16x32): col(n) = lane&15 = r, row(m) = q*4 + reg
__device__ __forceinline__ void epilogue(
    const f32x4 (&acc)[4][4], const float* __restrict__ b1,
    const float* __restrict__ w2, float* __restrict__ part,
    int bm, int bn, int wm, int wn, int q, int r)
{
  const int nbase = bn * 128 + wn * 64 + r;
  float b1v[4], w20[4], w21[4];
  #pragma unroll
  for (int t = 0; t < 4; ++t) {
    int n = nbase + t * 16;
    b1v[t] = b1[n];
    w20[t] = w2[2*n];
    w21[t] = w2[2*n + 1];
  }
  const int mbase = bm * 128 + wm * 64 + q * 4;
  #pragma unroll
  for (int tm = 0; tm < 4; ++tm) {
    #pragma unroll
    for (int v = 0; v < 4; ++v) {
      float s0 = 0.f, s1 = 0.f;
      #pragma unroll
      for (int tn = 0; tn < 4; ++tn) {
        float h = fmaxf(fmaf(acc[tm][tn][v], INV_W_SCALE, b1v[tn]), 0.f);
        s0 = fmaf(h, w20[tn], s0);
        s1 = fmaf(h, w21[tn], s1);
      }
      #pragma unroll
      for (int off = 1; off < 16; off <<= 1) {
        s0 += __shfl_xor(s0, off, 64);
        s1 += __shfl_xor(s1, off, 64);
      }
      if (r == 0) {
        int m = mbase + tm * 16 + v;
        atomicAdd(&part[2*m],     s0);
        atomicAdd(&part[2*m + 1], s1);
      }
    }
  }
}

// ---------- fused 4-pass MLP GEMM ----------
// acc_t = xh@twh^T + xl@twh^T + xh@twl^T ; acc_f = xh@fwh^T
// 5 operand tiles staged per BK=32 iter; 128x128 out tile; 4 waves 2x2.
__global__ __launch_bounds__(256, 2) void fused_mlp_kernel(
    const u16* __restrict__ xh, const u16* __restrict__ xl,
    const u16* __restrict__ twh, const u16* __restrict__ twl,
    const u16* __restrict__ fwh,
    const float* __restrict__ tb1, const float* __restrict__ tw2,
    const float* __restrict__ fb1, const float* __restrict__ fw2,
    float* __restrict__ tp, float* __restrict__ fp)
{
  // 5 tiles x 4096 u16 (8KB) = 40KB; fragment-ordered: tile t, group g(0..7),
  // lane l=q*16+r holds row g*16+r (g>>2 selects 64-half), k = q*8..q*8+7
  __shared__ __align__(16) u16 lds[5 * 4096];

  const int tid  = threadIdx.x;
  const int lane = tid & 63;
  const int wave = tid >> 6;
  const int wm = wave >> 1;
  const int wn = wave & 1;
  const int q  = lane >> 4;
  const int r  = lane & 15;

  // XCD-compact swizzle: hardware round-robins linear block id over 8 XCDs.
  // Give XCD x the bn-stripe [8x, 8x+8); within-XCD order: bn fastest, so the
  // ~64 co-resident blocks per XCD form an 8x8 (bm,bn) patch -> 8x L2 reuse.
  const int L  = blockIdx.x;
  const int s  = L >> 3;
  const int bm = s >> 3;              // 0..63
  const int bn = (L & 7) * 8 + (s & 7); // 0..63

  // staging: each wave loads groups {wave*2, wave*2+1} of all 5 tiles
  unsigned aoff[2], boff[2];
  int ldsg[2];
  #pragma unroll
  for (int j = 0; j < 2; ++j) {
    int g = wave * 2 + j;
    int row_in = (g >> 2) * 64 + (g & 3) * 16 + r;
    aoff[j] = (unsigned)(bm * 128 + row_in) * K_DIM + q * 8;
    boff[j] = (unsigned)(bn * 128 + row_in) * K_DIM + q * 8;
    ldsg[j] = g * 512;  // u16 index within a tile (wave-uniform base; HW adds lane*16B)
  }

  f32x4 at[4][4], af[4][4];
  #pragma unroll
  for (int i = 0; i < 4; ++i)
    #pragma unroll
    for (int j = 0; j < 4; ++j) {
      at[i][j] = (f32x4){0.f, 0.f, 0.f, 0.f};
      af[i][j] = (f32x4){0.f, 0.f, 0.f, 0.f};
    }

  for (int kk = 0; kk < K_DIM / 32; ++kk) {
    const unsigned ka = (unsigned)kk * 32u;
    __syncthreads();
    #pragma unroll
    for (int j = 0; j < 2; ++j) {
      GLOAD_LDS16(xh  + aoff[j] + ka, &lds[0*4096 + ldsg[j]]);
      GLOAD_LDS16(xl  + aoff[j] + ka, &lds[1*4096 + ldsg[j]]);
      GLOAD_LDS16(twh + boff[j] + ka, &lds[2*4096 + ldsg[j]]);
      GLOAD_LDS16(twl + boff[j] + ka, &lds[3*4096 + ldsg[j]]);
      GLOAD_LDS16(fwh + boff[j] + ka, &lds[4*4096 + ldsg[j]]);
    }
    __syncthreads();

    f16x8 ah[4], b0[4], tmp[4];
    #pragma unroll
    for (int t = 0; t < 4; ++t) {
      ah[t] = *reinterpret_cast<const f16x8*>(&lds[0*4096 + (wm*4 + t)*512 + lane*8]);
      b0[t] = *reinterpret_cast<const f16x8*>(&lds[2*4096 + (wn*4 + t)*512 + lane*8]);
    }
    #pragma unroll
    for (int tm = 0; tm < 4; ++tm)
      #pragma unroll
      for (int tn = 0; tn < 4; ++tn)
        at[tm][tn] = __builtin_amdgcn_mfma_f32_16x16x32_f16(ah[tm], b0[tn], at[tm][tn], 0, 0, 0);

    #pragma unroll
    for (int t = 0; t < 4; ++t)
      tmp[t] = *reinterpret_cast<const f16x8*>(&lds[1*4096 + (wm*4 + t)*512 + lane*8]);
    #pragma unroll
    for (int tm = 0; tm < 4; ++tm)
      #pragma unroll
      for (int tn = 0; tn < 4; ++tn)
        at[tm][tn] = __builtin_amdgcn_mfma_f32_16x16x32_f16(tmp[tm], b0[tn], at[tm][tn], 0, 0, 0);

    #pragma unroll
    for (int t = 0; t < 4; ++t)
      tmp[t] = *reinterpret_cast<const f16x8*>(&lds[3*4096 + (wn*4 + t)*512 + lane*8]);
    #pragma unroll
    for (int tm = 0; tm < 4; ++tm)
      #pragma unroll
      for (int tn = 0; tn < 4; ++tn)
        at[tm][tn] = __builtin_amdgcn_mfma_f32_16x16x32_f16(ah[tm], tmp[tn], at[tm][tn], 0, 0, 0);

    #pragma unroll
    for (int t = 0; t < 4; ++t)
      tmp[t] = *reinterpret_cast<const f16x8*>(&lds[4*4096 + (wn*4 + t)*512 + lane*8]);
    #pragma unroll
    for (int tm = 0; tm < 4; ++tm)
      #pragma unroll
      for (int tn = 0; tn < 4; ++tn)
        af[tm][tn] = __builtin_amdgcn_mfma_f32_16x16x32_f16(ah[tm], tmp[tn], af[tm][tn], 0, 0, 0);
  }

  epilogue(at, tb1, tw2, tp, bm, bn, wm, wn, q, r);
  epilogue(af, fb1, fw2, fp, bm, bn, wm, wn, q, r);
}

// ---------- confidence select ----------
__global__ void select_kernel(const float* __restrict__ tp, const float* __restrict__ fp,
                              float* __restrict__ out) {
  int m = blockIdx.x * blockDim.x + threadIdx.x;
  if (m >= B_ROWS) return;
  float a = tp[2*m], b = tp[2*m + 1];
  float conf = 1.0f / (1.0f + expf(-fabsf(a - b)));  // max softmax prob, C=2
  bool low = conf < 0.8f;
  out[2*m]     = low ? fp[2*m]     : a;
  out[2*m + 1] = low ? fp[2*m + 1] : b;
}

extern "C" void kernel_launch(void* const* d_in, const int* in_sizes, int n_in,
                              void* d_out, int out_size, void* d_ws, size_t ws_size,
                              hipStream_t stream) {
  const float* x    = (const float*)d_in[0];
  const float* t_w1 = (const float*)d_in[1];
  const float* t_b1 = (const float*)d_in[2];
  const float* t_w2 = (const float*)d_in[3];
  const float* t_b2 = (const float*)d_in[4];
  const float* f_w1 = (const float*)d_in[5];
  const float* f_b1 = (const float*)d_in[6];
  const float* f_w2 = (const float*)d_in[7];
  const float* f_b2 = (const float*)d_in[8];
  float* out = (float*)d_out;

  const size_t SZ = (size_t)B_ROWS * K_DIM * sizeof(u16);   // 64 MB
  const size_t NEED = 5 * SZ + 2 * (size_t)(2 * B_ROWS) * sizeof(float);
  if (ws_size < NEED) return;

  char* ws = (char*)d_ws;
  u16* x_hi   = (u16*)(ws);
  u16* x_lo   = (u16*)(ws + SZ);
  u16* twT_hi = (u16*)(ws + 2 * SZ);
  u16* twT_lo = (u16*)(ws + 3 * SZ);
  u16* fwT_hi = (u16*)(ws + 4 * SZ);
  float* t_part = (float*)(ws + 5 * SZ);
  float* f_part = t_part + 2 * B_ROWS;

  split_x_kernel<<<(B_ROWS * K_DIM / 4 + 255) / 256, 256, 0, stream>>>(
      (const float4*)x, (ushort4*)x_hi, (ushort4*)x_lo, B_ROWS * K_DIM / 4);
  dim3 tb(32, 8);
  transpose_split_kernel<<<dim3(H_DIM / 32, K_DIM / 32), tb, 0, stream>>>(
      t_w1, twT_hi, twT_lo, K_DIM, H_DIM);
  transpose_split_kernel<<<dim3(H_DIM / 32, K_DIM / 32), tb, 0, stream>>>(
      f_w1, fwT_hi, nullptr, K_DIM, H_DIM);
  init_parts_kernel<<<(2 * B_ROWS + 255) / 256, 256, 0, stream>>>(
      t_part, f_part, t_b2, f_b2);

  fused_mlp_kernel<<<(B_ROWS / 128) * (H_DIM / 128), 256, 0, stream>>>(
      x_hi, x_lo, twT_hi, twT_lo, fwT_hi,
      t_b1, t_w2, f_b1, f_w2, t_part, f_part);

  select_kernel<<<(B_ROWS + 255) / 256, 256, 0, stream>>>(t_part, f_part, out);
}

// Round 3
// 2868.005 us; speedup vs baseline: 1.4941x; 1.0866x over previous
//
#include <hip/hip_runtime.h>
#include <stdint.h>

typedef unsigned short u16;
typedef _Float16 f16x8 __attribute__((ext_vector_type(8)));
typedef float f32x4 __attribute__((ext_vector_type(4)));

#define B_ROWS 8192
#define K_DIM  4096
#define H_DIM  8192
#define W_SCALE 64.0f
#define INV_W_SCALE 0.015625f

// array strides within the contiguous ws region (u16 elements)
#define ARR_STRIDE (33554432u)   // 8192*4096

// ---------- f16 helpers ----------
__device__ __forceinline__ u16 f2h_bits(float f) {
  _Float16 h = (_Float16)f;
  return __builtin_bit_cast(u16, h);
}
__device__ __forceinline__ float h2f(u16 u) {
  return (float)__builtin_bit_cast(_Float16, u);
}

// ---------- direct global->LDS (width 16) ----------
typedef __attribute__((address_space(1))) void gvoid_t;
typedef __attribute__((address_space(3))) void lvoid_t;
#define GLOAD_LDS16(gp, lp) \
  __builtin_amdgcn_global_load_lds((gvoid_t*)(gp), (lvoid_t*)(lp), 16, 0, 0)

// ---------- x: fp32 -> f16 hi + f16 lo ----------
__global__ void split_x_kernel(const float4* __restrict__ x,
                               ushort4* __restrict__ hi,
                               ushort4* __restrict__ lo, int n4) {
  int i = blockIdx.x * blockDim.x + threadIdx.x;
  if (i >= n4) return;
  float4 v = x[i];
  ushort4 h, l;
  h.x = f2h_bits(v.x); l.x = f2h_bits(v.x - h2f(h.x));
  h.y = f2h_bits(v.y); l.y = f2h_bits(v.y - h2f(h.y));
  h.z = f2h_bits(v.z); l.z = f2h_bits(v.z - h2f(h.z));
  h.w = f2h_bits(v.w); l.w = f2h_bits(v.w - h2f(h.w));
  hi[i] = h; lo[i] = l;
}

// ---------- w1 [D,H] fp32 -> w1T [H,D] f16 hi (+lo), scaled by 64 ----------
__global__ void transpose_split_kernel(const float* __restrict__ w,
                                       u16* __restrict__ hi, u16* __restrict__ lo,
                                       int rows, int cols) {
  __shared__ float tile[32][33];
  int c0 = blockIdx.x * 32, r0 = blockIdx.y * 32;
  int tx = threadIdx.x, ty = threadIdx.y;
  #pragma unroll
  for (int j = 0; j < 4; ++j)
    tile[ty + j*8][tx] = w[(size_t)(r0 + ty + j*8) * cols + c0 + tx];
  __syncthreads();
  #pragma unroll
  for (int j = 0; j < 4; ++j) {
    int oc = c0 + ty + j*8;
    float v = tile[tx][ty + j*8] * W_SCALE;
    u16 h = f2h_bits(v);
    size_t oidx = (size_t)oc * rows + r0 + tx;
    hi[oidx] = h;
    if (lo) lo[oidx] = f2h_bits(v - h2f(h));
  }
}

// ---------- init logit accumulators with b2 ----------
__global__ void init_parts_kernel(float* __restrict__ tp, float* __restrict__ fp,
                                  const float* __restrict__ tb2,
                                  const float* __restrict__ fb2) {
  int i = blockIdx.x * blockDim.x + threadIdx.x;
  if (i < 2 * B_ROWS) { tp[i] = tb2[i & 1]; fp[i] = fb2[i & 1]; }
}

// ---------- fused layer-2 epilogue helper ----------
// C/D layout (16x16x32): col(n) = lane&15 = r, row(m) = q*4 + reg
__device__ __forceinline__ void epilogue(
    const f32x4 (&acc)[4][4], const float* __restrict__ b1,
    const float* __restrict__ w2, float* __restrict__ part,
    int mbase, int nbase, int r)
{
  float b1v[4], w20[4], w21[4];
  #pragma unroll
  for (int t = 0; t < 4; ++t) {
    int n = nbase + t * 16;
    b1v[t] = b1[n];
    w20[t] = w2[2*n];
    w21[t] = w2[2*n + 1];
  }
  #pragma unroll
  for (int tm = 0; tm < 4; ++tm) {
    #pragma unroll
    for (int v = 0; v < 4; ++v) {
      float s0 = 0.f, s1 = 0.f;
      #pragma unroll
      for (int tn = 0; tn < 4; ++tn) {
        float h = fmaxf(fmaf(acc[tm][tn][v], INV_W_SCALE, b1v[tn]), 0.f);
        s0 = fmaf(h, w20[tn], s0);
        s1 = fmaf(h, w21[tn], s1);
      }
      #pragma unroll
      for (int off = 1; off < 16; off <<= 1) {
        s0 += __shfl_xor(s0, off, 64);
        s1 += __shfl_xor(s1, off, 64);
      }
      if (r == 0) {
        int m = mbase + tm * 16 + v;
        atomicAdd(&part[2*m],     s0);
        atomicAdd(&part[2*m + 1], s1);
      }
    }
  }
}

// ---------- fused 4-pass MLP GEMM: 256x128 tile, 8 waves, dbuf BK=32 ----------
// acc_t = xh@twh^T + xl@twh^T + xh@twl^T ; acc_f = xh@fwh^T
// ws layout (u16, contiguous): xh | xl | twh | twl | fwh   (ARR_STRIDE each)
// LDS per buffer (u16 idx): xh[0,8192) xl[8192,16384) twh[16384,20480)
//                           twl[20480,24576) fwh[24576,28672)   (56 KB)
#define LBUF 28672
__global__ __launch_bounds__(512, 2) void fused_mlp_kernel(
    const u16* __restrict__ ws16,
    const float* __restrict__ tb1, const float* __restrict__ tw2,
    const float* __restrict__ fb1, const float* __restrict__ fw2,
    float* __restrict__ tp, float* __restrict__ fp)
{
  __shared__ __align__(16) u16 lds[2 * LBUF];   // 112 KB

  const int tid  = threadIdx.x;
  const int lane = tid & 63;
  const int wave = tid >> 6;          // 0..7
  const int wm = wave >> 1;           // 0..3 (m)
  const int wn = wave & 1;            // 0..1 (n)
  const int q  = lane >> 4;
  const int r  = lane & 15;

  // XCD-compact swizzle: grid 2048 = 32 bm x 64 bn. xcd = L&7 owns bn-stripe
  // [8*xcd, 8*xcd+8); the 32 co-resident blocks per XCD form a 4bm x 8bn patch.
  const int L  = blockIdx.x;
  const int s  = L >> 3;                          // 0..255
  const int bm = (s >> 5) * 4 + ((s >> 3) & 3);   // 0..31
  const int bn = (L & 7) * 8 + (s & 7);           // 0..63

  // ---- staging plan: 56 groups/iter (xh 16, xl 16, twh 8, twl 8, fwh 8),
  // 7 per wave. Group g of a tile: lane l=q*16+r holds row g*16+r, k=q*8..q*8+7
  unsigned goff[7];
  int loff[7];
  #pragma unroll
  for (int j = 0; j < 7; ++j) {
    int gid = wave * 7 + j;           // wave-uniform branches below
    unsigned arr; int g, lbase; bool isA;
    if (gid < 16)      { arr = 0; g = gid;      lbase = 0;     isA = true;  }
    else if (gid < 32) { arr = 1; g = gid - 16; lbase = 8192;  isA = true;  }
    else if (gid < 40) { arr = 2; g = gid - 32; lbase = 16384; isA = false; }
    else if (gid < 48) { arr = 3; g = gid - 40; lbase = 20480; isA = false; }
    else               { arr = 4; g = gid - 48; lbase = 24576; isA = false; }
    unsigned row = (isA ? (unsigned)bm * 256u : (unsigned)bn * 128u) + g * 16 + r;
    goff[j] = arr * ARR_STRIDE + row * (unsigned)K_DIM + q * 8;
    loff[j] = lbase + g * 512;
  }

  f32x4 at[4][4], af[4][4];
  #pragma unroll
  for (int i = 0; i < 4; ++i)
    #pragma unroll
    for (int j = 0; j < 4; ++j) {
      at[i][j] = (f32x4){0.f, 0.f, 0.f, 0.f};
      af[i][j] = (f32x4){0.f, 0.f, 0.f, 0.f};
    }

  // prologue: stage k-slice 0 into buffer 0
  #pragma unroll
  for (int j = 0; j < 7; ++j)
    GLOAD_LDS16(ws16 + goff[j], &lds[loff[j]]);

  int p = 0;
  for (int kk = 0; kk < K_DIM / 32; ++kk) {
    __syncthreads();   // drains this wave's pending loads (vmcnt 0) + barrier

    // prefetch next k-slice into the other buffer; overlaps with compute below
    if (kk + 1 < K_DIM / 32) {
      const unsigned ka = (unsigned)(kk + 1) * 32u;
      const int lb = (p ^ 1) * LBUF;
      #pragma unroll
      for (int j = 0; j < 7; ++j)
        GLOAD_LDS16(ws16 + goff[j] + ka, &lds[lb + loff[j]]);
    }

    const int base = p * LBUF;
    f16x8 ah[4], bb[4], tmp[4];
    #pragma unroll
    for (int t = 0; t < 4; ++t) {
      ah[t] = *reinterpret_cast<const f16x8*>(&lds[base + (wm*4 + t)*512 + lane*8]);           // xh
      bb[t] = *reinterpret_cast<const f16x8*>(&lds[base + 16384 + (wn*4 + t)*512 + lane*8]);   // twh
    }
    #pragma unroll
    for (int tm = 0; tm < 4; ++tm)
      #pragma unroll
      for (int tn = 0; tn < 4; ++tn)
        at[tm][tn] = __builtin_amdgcn_mfma_f32_16x16x32_f16(ah[tm], bb[tn], at[tm][tn], 0, 0, 0);

    #pragma unroll
    for (int t = 0; t < 4; ++t)
      tmp[t] = *reinterpret_cast<const f16x8*>(&lds[base + 8192 + (wm*4 + t)*512 + lane*8]);   // xl
    #pragma unroll
    for (int tm = 0; tm < 4; ++tm)
      #pragma unroll
      for (int tn = 0; tn < 4; ++tn)
        at[tm][tn] = __builtin_amdgcn_mfma_f32_16x16x32_f16(tmp[tm], bb[tn], at[tm][tn], 0, 0, 0);

    #pragma unroll
    for (int t = 0; t < 4; ++t)
      tmp[t] = *reinterpret_cast<const f16x8*>(&lds[base + 20480 + (wn*4 + t)*512 + lane*8]);  // twl
    #pragma unroll
    for (int tm = 0; tm < 4; ++tm)
      #pragma unroll
      for (int tn = 0; tn < 4; ++tn)
        at[tm][tn] = __builtin_amdgcn_mfma_f32_16x16x32_f16(ah[tm], tmp[tn], at[tm][tn], 0, 0, 0);

    #pragma unroll
    for (int t = 0; t < 4; ++t)
      tmp[t] = *reinterpret_cast<const f16x8*>(&lds[base + 24576 + (wn*4 + t)*512 + lane*8]);  // fwh
    #pragma unroll
    for (int tm = 0; tm < 4; ++tm)
      #pragma unroll
      for (int tn = 0; tn < 4; ++tn)
        af[tm][tn] = __builtin_amdgcn_mfma_f32_16x16x32_f16(ah[tm], tmp[tn], af[tm][tn], 0, 0, 0);

    p ^= 1;
  }

  const int mbase = bm * 256 + wm * 64 + q * 4;
  const int nbase = bn * 128 + wn * 64 + r;
  epilogue(at, tb1, tw2, tp, mbase, nbase, r);
  epilogue(af, fb1, fw2, fp, mbase, nbase, r);
}

// ---------- confidence select ----------
__global__ void select_kernel(const float* __restrict__ tp, const float* __restrict__ fp,
                              float* __restrict__ out) {
  int m = blockIdx.x * blockDim.x + threadIdx.x;
  if (m >= B_ROWS) return;
  float a = tp[2*m], b = tp[2*m + 1];
  float conf = 1.0f / (1.0f + expf(-fabsf(a - b)));  // max softmax prob, C=2
  bool low = conf < 0.8f;
  out[2*m]     = low ? fp[2*m]     : a;
  out[2*m + 1] = low ? fp[2*m + 1] : b;
}

extern "C" void kernel_launch(void* const* d_in, const int* in_sizes, int n_in,
                              void* d_out, int out_size, void* d_ws, size_t ws_size,
                              hipStream_t stream) {
  const float* x    = (const float*)d_in[0];
  const float* t_w1 = (const float*)d_in[1];
  const float* t_b1 = (const float*)d_in[2];
  const float* t_w2 = (const float*)d_in[3];
  const float* t_b2 = (const float*)d_in[4];
  const float* f_w1 = (const float*)d_in[5];
  const float* f_b1 = (const float*)d_in[6];
  const float* f_w2 = (const float*)d_in[7];
  const float* f_b2 = (const float*)d_in[8];
  float* out = (float*)d_out;

  const size_t SZ = (size_t)B_ROWS * K_DIM * sizeof(u16);   // 64 MB
  const size_t NEED = 5 * SZ + 2 * (size_t)(2 * B_ROWS) * sizeof(float);
  if (ws_size < NEED) return;

  char* ws = (char*)d_ws;
  u16* x_hi   = (u16*)(ws);
  u16* x_lo   = (u16*)(ws + SZ);
  u16* twT_hi = (u16*)(ws + 2 * SZ);
  u16* twT_lo = (u16*)(ws + 3 * SZ);
  u16* fwT_hi = (u16*)(ws + 4 * SZ);
  float* t_part = (float*)(ws + 5 * SZ);
  float* f_part = t_part + 2 * B_ROWS;

  split_x_kernel<<<(B_ROWS * K_DIM / 4 + 255) / 256, 256, 0, stream>>>(
      (const float4*)x, (ushort4*)x_hi, (ushort4*)x_lo, B_ROWS * K_DIM / 4);
  dim3 tb(32, 8);
  transpose_split_kernel<<<dim3(H_DIM / 32, K_DIM / 32), tb, 0, stream>>>(
      t_w1, twT_hi, twT_lo, K_DIM, H_DIM);
  transpose_split_kernel<<<dim3(H_DIM / 32, K_DIM / 32), tb, 0, stream>>>(
      f_w1, fwT_hi, nullptr, K_DIM, H_DIM);
  init_parts_kernel<<<(2 * B_ROWS + 255) / 256, 256, 0, stream>>>(
      t_part, f_part, t_b2, f_b2);

  fused_mlp_kernel<<<(B_ROWS / 256) * (H_DIM / 128), 512, 0, stream>>>(
      x_hi, t_b1, t_w2, f_b1, f_w2, t_part, f_part);

  select_kernel<<<(B_ROWS + 255) / 256, 256, 0, stream>>>(t_part, f_part, out);
}